// Round 1
// baseline (424.597 us; speedup 1.0000x reference)
//
#include <hip/hip_runtime.h>
#include <hip/hip_bf16.h>

// Problem constants (from reference): B,Q,C,P,A = 32,300,81,300,29
#define BB 32
#define QQ 300
#define CC 81
#define PP 300
#define AA 29

// Flat output layout (fp32 elements), concatenated in reference return order:
// scores(B,Q) | labels(B,Q) | boxes(B,Q,4) | score(B,A,Q,Q+1) | h_mask(B,Q) | o_mask(B,Q+1)
constexpr long long OFF_SCORES = 0;
constexpr long long OFF_LABELS = OFF_SCORES + (long long)BB * QQ;            // 9600
constexpr long long OFF_BOXES  = OFF_LABELS + (long long)BB * QQ;            // 19200
constexpr long long OFF_SCORE  = OFF_BOXES  + (long long)BB * QQ * 4;        // 57600
constexpr long long SCORE_ELEMS = (long long)BB * AA * QQ * (QQ + 1);        // 83,798,400
constexpr long long OFF_HMASK  = OFF_SCORE + SCORE_ELEMS;                    // 83,856,000
constexpr long long OFF_OMASK  = OFF_HMASK + (long long)BB * QQ;             // 83,865,600
// total = 83,875,232 elements

typedef float f32x4 __attribute__((ext_vector_type(4)));

// Custom zero-fill of the score region. Replaces hipMemsetAsync, whose rocclr
// fill kernel measured ~240 us (either 4x write amplification or ~1.4 TB/s real
// BW per WRITE_SIZE). 16B nontemporal stores, grid-stride, streaming regime.
// SCORE_ELEMS % 4 == 0 and (OFF_SCORE*4) % 16 == 0, so float4 stores are exact
// and aligned.
__global__ __launch_bounds__(256) void zero_score_kernel(float* __restrict__ out) {
    f32x4* p = (f32x4*)(out + OFF_SCORE);
    const int n4 = (int)(SCORE_ELEMS / 4);   // 20,949,600 — fits in int
    int i = blockIdx.x * blockDim.x + threadIdx.x;
    const int stride = gridDim.x * blockDim.x;
    f32x4 z = (f32x4)0.0f;
    for (; i < n4; i += stride) {
        __builtin_nontemporal_store(z, p + i);
    }
}

// One thread per (b,q): softmax max/argmax, boxes, masks.
__global__ void cls_box_mask_kernel(const float* __restrict__ logits,
                                    const float* __restrict__ boxes_in,
                                    const float* __restrict__ tsize,
                                    float* __restrict__ out) {
    int t = blockIdx.x * blockDim.x + threadIdx.x;
    if (t >= BB * QQ) return;
    int b = t / QQ;
    int q = t - b * QQ;

    const float* l = logits + (long long)t * CC;

    // Pass 1: global max (all 81) + max/argmax over first 80 (first-index tie-break).
    float m = -1e30f;
    float best = -1e30f;
    int am = 0;
    for (int c = 0; c < CC; ++c) {
        float x = l[c];
        m = fmaxf(m, x);
        if (c < CC - 1 && x > best) { best = x; am = c; }
    }
    // Pass 2: softmax denominator (loads hit L1).
    float s = 0.0f;
    for (int c = 0; c < CC; ++c) {
        s += __expf(l[c] - m);
    }
    float score = __expf(best - m) / s;

    out[OFF_SCORES + t] = score;
    out[OFF_LABELS + t] = (float)am;

    // Boxes: cxcywh -> xyxy, scaled by [img_w, img_h, img_w, img_h].
    float cx = boxes_in[4 * (long long)t + 0];
    float cy = boxes_in[4 * (long long)t + 1];
    float w  = boxes_in[4 * (long long)t + 2];
    float h  = boxes_in[4 * (long long)t + 3];
    float img_h = tsize[2 * b + 0];
    float img_w = tsize[2 * b + 1];
    out[OFF_BOXES + 4 * (long long)t + 0] = (cx - 0.5f * w) * img_w;
    out[OFF_BOXES + 4 * (long long)t + 1] = (cy - 0.5f * h) * img_h;
    out[OFF_BOXES + 4 * (long long)t + 2] = (cx + 0.5f * w) * img_w;
    out[OFF_BOXES + 4 * (long long)t + 3] = (cy + 0.5f * h) * img_h;

    // Masks (threshold = 0.0).
    out[OFF_HMASK + t] = (am == 1 && score > 0.0f) ? 1.0f : 0.0f;
    out[OFF_OMASK + (long long)b * (QQ + 1) + q] = (score > 0.0f) ? 1.0f : 0.0f;
    if (q == 0) out[OFF_OMASK + (long long)b * (QQ + 1) + QQ] = 1.0f;
}

// One block per batch b; thread p handles pair p. Scatter sigmoid(actions) into
// out[b, a, h, o'] with o' = (h==o ? Q : o); numpy duplicate semantics: last p wins.
// Auto-detects int64 vs int32 storage of pred_rel_pairs: values are in [0, 300),
// so if stored little-endian int64, every odd 32-bit word is zero.
__global__ void scatter_kernel(const int* __restrict__ pairs,
                               const float* __restrict__ actions,
                               float* __restrict__ out) {
    __shared__ int keys[PP];
    __shared__ int nz;
    int tid = threadIdx.x;
    if (tid == 0) nz = 0;
    __syncthreads();

    int local = 0;
    for (int i = tid; i < BB * PP; i += blockDim.x) local |= pairs[2 * i + 1];
    if (local) atomicOr(&nz, 1);
    __syncthreads();
    bool is64 = (nz == 0);

    int b = blockIdx.x;
    int p = tid;
    int h = -1, o = -1;
    if (p < PP) {
        if (is64) {
            h = pairs[((long long)(b * PP + p)) * 4 + 0];
            o = pairs[((long long)(b * PP + p)) * 4 + 2];
        } else {
            h = pairs[((long long)(b * PP + p)) * 2 + 0];
            o = pairs[((long long)(b * PP + p)) * 2 + 1];
        }
        if (h == o) o = QQ;
        keys[p] = h * (QQ + 1) + o;
    }
    __syncthreads();
    if (p >= PP) return;

    int k = keys[p];
    for (int p2 = p + 1; p2 < PP; ++p2) {
        if (keys[p2] == k) return;  // a later pair writes the same slot: it wins
    }

    const float* act = actions + (long long)(b * PP + p) * AA;
    long long base = OFF_SCORE + (long long)b * AA * QQ * (QQ + 1)
                   + (long long)h * (QQ + 1) + o;
    for (int a = 0; a < AA; ++a) {
        float x = act[a];
        float sg = 1.0f / (1.0f + __expf(-x));
        out[base + (long long)a * QQ * (QQ + 1)] = sg;
    }
}

extern "C" void kernel_launch(void* const* d_in, const int* in_sizes, int n_in,
                              void* d_out, int out_size, void* d_ws, size_t ws_size,
                              hipStream_t stream) {
    const float* logits   = (const float*)d_in[0]; // (B,Q,C)
    const float* boxes_in = (const float*)d_in[1]; // (B,Q,4)
    const float* actions  = (const float*)d_in[2]; // (B,P,A)
    const int*   pairs    = (const int*)d_in[3];   // (B,P,2) int
    const float* tsize    = (const float*)d_in[4]; // (B,2)
    float* out = (float*)d_out;

    // Custom zero-fill of the score region (replaces hipMemsetAsync, ~240us).
    zero_score_kernel<<<2048, 256, 0, stream>>>(out);

    int n = BB * QQ;
    cls_box_mask_kernel<<<(n + 255) / 256, 256, 0, stream>>>(logits, boxes_in, tsize, out);
    scatter_kernel<<<BB, 320, 0, stream>>>(pairs, actions, out);
}

// Round 2
// 414.129 us; speedup vs baseline: 1.0253x; 1.0253x over previous
//
#include <hip/hip_runtime.h>
#include <hip/hip_bf16.h>

// Problem constants (from reference): B,Q,C,P,A = 32,300,81,300,29
#define BB 32
#define QQ 300
#define CC 81
#define PP 300
#define AA 29

// Flat output layout (fp32 elements), concatenated in reference return order:
// scores(B,Q) | labels(B,Q) | boxes(B,Q,4) | score(B,A,Q,Q+1) | h_mask(B,Q) | o_mask(B,Q+1)
constexpr long long OFF_SCORES = 0;
constexpr long long OFF_LABELS = OFF_SCORES + (long long)BB * QQ;            // 9600
constexpr long long OFF_BOXES  = OFF_LABELS + (long long)BB * QQ;            // 19200
constexpr long long OFF_SCORE  = OFF_BOXES  + (long long)BB * QQ * 4;        // 57600
constexpr long long SCORE_ELEMS = (long long)BB * AA * QQ * (QQ + 1);        // 83,798,400
constexpr long long OFF_HMASK  = OFF_SCORE + SCORE_ELEMS;                    // 83,856,000
constexpr long long OFF_OMASK  = OFF_HMASK + (long long)BB * QQ;             // 83,865,600
// total = 83,875,232 elements

constexpr int SLOTS = QQ * (QQ + 1);          // 90,300 slots per (b,a) plane
constexpr int SLOT4 = SLOTS / 4;              // 22,575 float4 per plane (exact)
constexpr size_t LUT_BYTES = (size_t)BB * SLOTS * sizeof(int);  // 11.56 MB

typedef float f32x4 __attribute__((ext_vector_type(4)));

// ---------------------------------------------------------------------------
// Kernel 1: build slot->pair LUT in workspace. One block per batch: init own
// slice to -1, then scatter p via atomicMax (larger p = later pair = numpy
// last-wins). Auto-detects int64 vs int32 pred_rel_pairs (values < 300, so
// int64 little-endian => every odd 32-bit word is zero).
__global__ __launch_bounds__(512) void lut_build_kernel(const int* __restrict__ pairs,
                                                        int* __restrict__ lut) {
    __shared__ int nz;
    int tid = threadIdx.x;
    int b = blockIdx.x;
    if (tid == 0) nz = 0;
    __syncthreads();

    int local = 0;
    for (int i = tid; i < BB * PP; i += blockDim.x) local |= pairs[2 * i + 1];
    if (local) atomicOr(&nz, 1);

    // init this batch's LUT slice to -1 (int4 stores, 16B-aligned: 90300*4 % 16 == 0)
    int4* lb4 = (int4*)(lut + b * SLOTS);
    int4 m1 = make_int4(-1, -1, -1, -1);
    for (int i = tid; i < SLOT4; i += blockDim.x) lb4[i] = m1;
    __syncthreads();
    bool is64 = (nz == 0);

    if (tid < PP) {
        int h, o;
        if (is64) {
            h = pairs[((long long)(b * PP + tid)) * 4 + 0];
            o = pairs[((long long)(b * PP + tid)) * 4 + 2];
        } else {
            h = pairs[((long long)(b * PP + tid)) * 2 + 0];
            o = pairs[((long long)(b * PP + tid)) * 2 + 1];
        }
        if (h == o) o = QQ;
        atomicMax(&lut[b * SLOTS + h * (QQ + 1) + o], tid);
    }
}

// ---------------------------------------------------------------------------
// Kernel 2 (unchanged, verified): one thread per (b,q): softmax max/argmax,
// boxes, masks.
__global__ void cls_box_mask_kernel(const float* __restrict__ logits,
                                    const float* __restrict__ boxes_in,
                                    const float* __restrict__ tsize,
                                    float* __restrict__ out) {
    int t = blockIdx.x * blockDim.x + threadIdx.x;
    if (t >= BB * QQ) return;
    int b = t / QQ;
    int q = t - b * QQ;

    const float* l = logits + (long long)t * CC;

    float m = -1e30f;
    float best = -1e30f;
    int am = 0;
    for (int c = 0; c < CC; ++c) {
        float x = l[c];
        m = fmaxf(m, x);
        if (c < CC - 1 && x > best) { best = x; am = c; }
    }
    float s = 0.0f;
    for (int c = 0; c < CC; ++c) {
        s += __expf(l[c] - m);
    }
    float score = __expf(best - m) / s;

    out[OFF_SCORES + t] = score;
    out[OFF_LABELS + t] = (float)am;

    float cx = boxes_in[4 * (long long)t + 0];
    float cy = boxes_in[4 * (long long)t + 1];
    float w  = boxes_in[4 * (long long)t + 2];
    float h  = boxes_in[4 * (long long)t + 3];
    float img_h = tsize[2 * b + 0];
    float img_w = tsize[2 * b + 1];
    out[OFF_BOXES + 4 * (long long)t + 0] = (cx - 0.5f * w) * img_w;
    out[OFF_BOXES + 4 * (long long)t + 1] = (cy - 0.5f * h) * img_h;
    out[OFF_BOXES + 4 * (long long)t + 2] = (cx + 0.5f * w) * img_w;
    out[OFF_BOXES + 4 * (long long)t + 3] = (cy + 0.5f * h) * img_h;

    out[OFF_HMASK + t] = (am == 1 && score > 0.0f) ? 1.0f : 0.0f;
    out[OFF_OMASK + (long long)b * (QQ + 1) + q] = (score > 0.0f) ? 1.0f : 0.0f;
    if (q == 0) out[OFF_OMASK + (long long)b * (QQ + 1) + QQ] = 1.0f;
}

// ---------------------------------------------------------------------------
// Kernel 3: fused single-pass writer of the entire score tensor. Each block:
// (a = blockIdx.x, chunk = blockIdx.y, b = blockIdx.z); 256 threads x 4 float4
// = 1024 consecutive float4 of one (b,a) plane. Plain cached stores (NT stores
// measured slower in R1). Blocks consecutive in dispatch order share the same
// 16KB LUT chunk (a varies fastest) -> L2-hot LUT, HBM fetch ~= 11.6 MB once.
__global__ __launch_bounds__(256) void score_write_kernel(const int* __restrict__ lut,
                                                          const float* __restrict__ actions,
                                                          float* __restrict__ out) {
    int a = blockIdx.x;                 // 0..28
    int chunk = blockIdx.y;             // 0..22
    int b = blockIdx.z;                 // 0..31
    const int4* lb4 = (const int4*)(lut + b * SLOTS);
    const float* actb = actions + (long long)b * PP * AA + a;
    f32x4* plane4 = (f32x4*)(out + OFF_SCORE + (long long)(b * AA + a) * SLOTS);

    int s4 = chunk * 1024 + threadIdx.x;
    #pragma unroll
    for (int k = 0; k < 4; ++k, s4 += 256) {
        if (s4 >= SLOT4) break;
        int4 pi = lb4[s4];
        f32x4 v = (f32x4)0.0f;
        // Per-lane predicated loads: masked lanes don't issue the gather, so no
        // OOB access for empty (-1) slots. Hit rate ~0.33%, so the exp path is
        // rarely taken per-wave.
        if (pi.x >= 0) v.x = 1.0f / (1.0f + __expf(-actb[pi.x * AA]));
        if (pi.y >= 0) v.y = 1.0f / (1.0f + __expf(-actb[pi.y * AA]));
        if (pi.z >= 0) v.z = 1.0f / (1.0f + __expf(-actb[pi.z * AA]));
        if (pi.w >= 0) v.w = 1.0f / (1.0f + __expf(-actb[pi.w * AA]));
        plane4[s4] = v;
    }
}

// ---------------------------------------------------------------------------
// Fallback path (workspace too small): old zero + scatter structure.
__global__ void scatter_kernel(const int* __restrict__ pairs,
                               const float* __restrict__ actions,
                               float* __restrict__ out) {
    __shared__ int keys[PP];
    __shared__ int nz;
    int tid = threadIdx.x;
    if (tid == 0) nz = 0;
    __syncthreads();

    int local = 0;
    for (int i = tid; i < BB * PP; i += blockDim.x) local |= pairs[2 * i + 1];
    if (local) atomicOr(&nz, 1);
    __syncthreads();
    bool is64 = (nz == 0);

    int b = blockIdx.x;
    int p = tid;
    int h = -1, o = -1;
    if (p < PP) {
        if (is64) {
            h = pairs[((long long)(b * PP + p)) * 4 + 0];
            o = pairs[((long long)(b * PP + p)) * 4 + 2];
        } else {
            h = pairs[((long long)(b * PP + p)) * 2 + 0];
            o = pairs[((long long)(b * PP + p)) * 2 + 1];
        }
        if (h == o) o = QQ;
        keys[p] = h * (QQ + 1) + o;
    }
    __syncthreads();
    if (p >= PP) return;

    int k = keys[p];
    for (int p2 = p + 1; p2 < PP; ++p2) {
        if (keys[p2] == k) return;
    }

    const float* act = actions + (long long)(b * PP + p) * AA;
    long long base = OFF_SCORE + (long long)b * AA * QQ * (QQ + 1)
                   + (long long)h * (QQ + 1) + o;
    for (int a = 0; a < AA; ++a) {
        float x = act[a];
        float sg = 1.0f / (1.0f + __expf(-x));
        out[base + (long long)a * QQ * (QQ + 1)] = sg;
    }
}

extern "C" void kernel_launch(void* const* d_in, const int* in_sizes, int n_in,
                              void* d_out, int out_size, void* d_ws, size_t ws_size,
                              hipStream_t stream) {
    const float* logits   = (const float*)d_in[0]; // (B,Q,C)
    const float* boxes_in = (const float*)d_in[1]; // (B,Q,4)
    const float* actions  = (const float*)d_in[2]; // (B,P,A)
    const int*   pairs    = (const int*)d_in[3];   // (B,P,2) int
    const float* tsize    = (const float*)d_in[4]; // (B,2)
    float* out = (float*)d_out;

    int n = BB * QQ;
    if (d_ws != nullptr && ws_size >= LUT_BYTES) {
        int* lut = (int*)d_ws;
        // 1. slot->pair LUT (per-batch init + atomicMax scatter, self-contained per block)
        lut_build_kernel<<<BB, 512, 0, stream>>>(pairs, lut);
        // 2. small outputs (independent)
        cls_box_mask_kernel<<<(n + 255) / 256, 256, 0, stream>>>(logits, boxes_in, tsize, out);
        // 3. single streaming pass over the full score tensor
        score_write_kernel<<<dim3(AA, (SLOT4 + 1023) / 1024, BB), 256, 0, stream>>>(lut, actions, out);
    } else {
        // Fallback: previous verified structure.
        hipMemsetAsync((char*)d_out + OFF_SCORE * sizeof(float), 0,
                       (size_t)SCORE_ELEMS * sizeof(float), stream);
        cls_box_mask_kernel<<<(n + 255) / 256, 256, 0, stream>>>(logits, boxes_in, tsize, out);
        scatter_kernel<<<BB, 320, 0, stream>>>(pairs, actions, out);
    }
}